// Round 1
// baseline (630.358 us; speedup 1.0000x reference)
//
#include <hip/hip_runtime.h>
#include <stdint.h>

// StraightThroughSubsetSampler: out = khot(top_k(scores/tau + gumbel_noise, k))
// Forward value of khot + soft - stop_grad(soft) == khot (+ ~1e-7 residue).
//
// One block per row. Radix-select (4x 8-bit passes over sortable-u32 keys)
// finds the kth-largest key; output is a >= compare. Ties at the boundary are
// resolved lowest-index-first (stable top_k semantics) via a rare slow path.

namespace {

constexpr int kN = 8192;        // row length (N_NODES)
constexpr int kThreads = 256;   // 4 waves
constexpr int kVPT = kN / (kThreads * 4);  // 8 float4 per thread
constexpr int kEPT = kN / kThreads;        // 32 elements per thread

typedef float f32x4 __attribute__((ext_vector_type(4)));

__device__ __forceinline__ uint32_t f2sortable(float x) {
  uint32_t b = __float_as_uint(x);
  // monotonic float->uint: larger float => larger uint
  return (b & 0x80000000u) ? ~b : (b | 0x80000000u);
}

__global__ __launch_bounds__(kThreads, 4) void st_topk_khot(
    const float* __restrict__ scores, const float* __restrict__ noise,
    const float* __restrict__ tau_p, const int* __restrict__ k_p,
    float* __restrict__ out) {
  __shared__ uint32_t sdata[kN];           // 32 KiB key mirror (tie slow path)
  __shared__ uint32_t hist[kThreads];      // 256-bin histogram
  __shared__ uint32_t cum[kThreads + 1];   // suffix sums
  __shared__ uint32_t bcast[3];            // prefix / desired / eq

  const int t = threadIdx.x;
  const size_t row = blockIdx.x;
  const float tau = tau_p[0];
  const uint32_t k = (uint32_t)k_p[0];

  const float4* s4 = reinterpret_cast<const float4*>(scores + row * (size_t)kN);
  const float4* g4 = reinterpret_cast<const float4*>(noise + row * (size_t)kN);
  uint4* sd4 = reinterpret_cast<uint4*>(sdata);

  uint32_t u[kEPT];

  // ---- load, compute keys (bit-exact vs reference: div, then add) ----
#pragma unroll
  for (int i = 0; i < kVPT; ++i) {
    const int vi = i * kThreads + t;
    float4 s = s4[vi];
    float4 g = g4[vi];
    uint4 q;
    q.x = f2sortable(s.x / tau + g.x);
    q.y = f2sortable(s.y / tau + g.y);
    q.z = f2sortable(s.z / tau + g.z);
    q.w = f2sortable(s.w / tau + g.w);
    u[i * 4 + 0] = q.x;
    u[i * 4 + 1] = q.y;
    u[i * 4 + 2] = q.z;
    u[i * 4 + 3] = q.w;
    sd4[vi] = q;
  }

  // ---- radix select: kth largest key ----
  uint32_t prefix = 0, pmask = 0, desired = k, eq = 0;

#pragma unroll
  for (int pass = 0; pass < 4; ++pass) {
    const int shift = 24 - pass * 8;
    hist[t] = 0;
    __syncthreads();

    if (pass == 0) {
      // Exponent byte is heavily skewed -> ballot-aggregate to avoid 64-way
      // same-address LDS atomic serialization. One atomic per bin per wave.
#pragma unroll
      for (int e = 0; e < kEPT; ++e) {
        const uint32_t b = u[e] >> 24;
        uint64_t m = ~0ull;
#pragma unroll
        for (int bit = 0; bit < 8; ++bit) {
          const uint64_t bal = __ballot((int)((b >> bit) & 1u));
          m &= ((b >> bit) & 1u) ? bal : ~bal;
        }
        if ((threadIdx.x & 63) == __builtin_ctzll(m))
          atomicAdd(&hist[b], (uint32_t)__popcll(m));
      }
    } else {
      // few elements still match prefix -> plain atomics are cheap
#pragma unroll
      for (int e = 0; e < kEPT; ++e) {
        if ((u[e] & pmask) == prefix)
          atomicAdd(&hist[(u[e] >> shift) & 255u], 1u);
      }
    }
    __syncthreads();

    // suffix sum: cum[b] = #elements (matching prefix) with digit >= b
    cum[t] = hist[t];
    if (t == 0) cum[kThreads] = 0;
#pragma unroll
    for (int off = 1; off < kThreads; off <<= 1) {
      __syncthreads();
      const uint32_t add = (t + off < kThreads) ? cum[t + off] : 0u;
      __syncthreads();
      cum[t] += add;
    }
    __syncthreads();

    const uint32_t cb = cum[t];
    const uint32_t cb1 = cum[t + 1];
    if (cb >= desired && cb1 < desired) {  // unique winner: cum is monotone
      bcast[0] = prefix | ((uint32_t)t << shift);
      bcast[1] = desired - cb1;  // still needed from this digit's bin
      bcast[2] = cb - cb1;       // #keys with this digit (== #ties on last pass)
    }
    __syncthreads();
    prefix = bcast[0];
    desired = bcast[1];
    eq = bcast[2];
    pmask |= 0xFFu << shift;
    __syncthreads();
  }

  const uint32_t thr = prefix;  // exact key of the kth largest

  // ---- rare path: ties straddle the k boundary; keep lowest indices ----
  if (eq != desired) {  // block-uniform condition
    if (t == 0) {
      uint32_t need = desired;
      for (int j = 0; j < kN; ++j) {
        if (sdata[j] == thr) {
          if (need) {
            --need;
          } else {
            sdata[j] = 0u;  // demote below thr -> excluded
          }
        }
      }
    }
    __syncthreads();
#pragma unroll
    for (int i = 0; i < kVPT; ++i) {
      uint4 q = sd4[i * kThreads + t];
      u[i * 4 + 0] = q.x;
      u[i * 4 + 1] = q.y;
      u[i * 4 + 2] = q.z;
      u[i * 4 + 3] = q.w;
    }
  }

  // ---- write k-hot row (streaming stores; out is never re-read) ----
  f32x4* o4 = reinterpret_cast<f32x4*>(out + row * (size_t)kN);
#pragma unroll
  for (int i = 0; i < kVPT; ++i) {
    const int vi = i * kThreads + t;
    f32x4 o;
    o.x = (u[i * 4 + 0] >= thr) ? 1.0f : 0.0f;
    o.y = (u[i * 4 + 1] >= thr) ? 1.0f : 0.0f;
    o.z = (u[i * 4 + 2] >= thr) ? 1.0f : 0.0f;
    o.w = (u[i * 4 + 3] >= thr) ? 1.0f : 0.0f;
    __builtin_nontemporal_store(o, o4 + vi);
  }
}

}  // namespace

extern "C" void kernel_launch(void* const* d_in, const int* in_sizes, int n_in,
                              void* d_out, int out_size, void* d_ws, size_t ws_size,
                              hipStream_t stream) {
  (void)in_sizes;
  (void)n_in;
  (void)d_ws;
  (void)ws_size;
  (void)out_size;
  const float* scores = (const float*)d_in[0];
  const float* noise = (const float*)d_in[1];
  const float* tau_p = (const float*)d_in[2];
  const int* k_p = (const int*)d_in[3];
  float* out = (float*)d_out;

  hipLaunchKernelGGL(st_topk_khot, dim3(kN), dim3(kThreads), 0, stream,
                     scores, noise, tau_p, k_p, out);
}